// Round 8
// baseline (836.250 us; speedup 1.0000x reference)
//
#include <hip/hip_runtime.h>
#include <hip/hip_bf16.h>

#define S 8192
#define D 1024
#define QBLK 32
#define NW 8
#define KVBLK 256        // 8 waves x 32 k-rows
#define NITER (S/KVBLK)  // 32
#define NTHR (NW*64)     // 512

typedef short short8 __attribute__((ext_vector_type(8)));
typedef float f32x16 __attribute__((ext_vector_type(16)));

__device__ __forceinline__ unsigned short f2bf(float x) {
    unsigned u = __builtin_bit_cast(unsigned, x);
    u += 0x7FFFu + ((u >> 16) & 1u);   // RNE
    return (unsigned short)(u >> 16);
}
__device__ __forceinline__ float fexp2(float x) { return __builtin_amdgcn_exp2f(x); }

// 16B logical LDS read/write with 8B-granule XOR swizzle (two b64 ops)
__device__ __forceinline__ short8 lds_r16(const char* rowbase, int off, int swz) {
    uint2 a = *(const uint2*)(rowbase + (off ^ swz));
    uint2 b = *(const uint2*)(rowbase + ((off + 8) ^ swz));
    int4 w; w.x = (int)a.x; w.y = (int)a.y; w.z = (int)b.x; w.w = (int)b.y;
    return __builtin_bit_cast(short8, w);
}
__device__ __forceinline__ void lds_w16(char* rowbase, int off, int swz, short8 v) {
    int4 w = __builtin_bit_cast(int4, v);
    uint2 a; a.x = (unsigned)w.x; a.y = (unsigned)w.y;
    uint2 b; b.x = (unsigned)w.z; b.y = (unsigned)w.w;
    *(uint2*)(rowbase + (off ^ swz))       = a;
    *(uint2*)(rowbase + ((off + 8) ^ swz)) = b;
}

// ---- prep: K fp32 [S][D] -> fragment-ordered bf16 ----
// out[ ((kt*64 + dc)*64 + lane)*8 + j ] = K[kt*32 + (lane&31)][dc*16 + (lane>>5)*8 + j]
__global__ void pack_k_kernel(const float* __restrict__ in, unsigned short* __restrict__ out) {
    int idx  = blockIdx.x * 256 + threadIdx.x;
    int lane = idx & 63, dc = (idx >> 6) & 63, kt = idx >> 12;
    int row = kt * 32 + (lane & 31), col = dc * 16 + (lane >> 5) * 8;
    const float4* p = (const float4*)(in + (size_t)row * D + col);
    float4 a = p[0], b = p[1];
    short8 v;
    v[0] = (short)f2bf(a.x); v[1] = (short)f2bf(a.y); v[2] = (short)f2bf(a.z); v[3] = (short)f2bf(a.w);
    v[4] = (short)f2bf(b.x); v[5] = (short)f2bf(b.y); v[6] = (short)f2bf(b.z); v[7] = (short)f2bf(b.w);
    *(short8*)(out + (size_t)idx * 8) = v;
}

// ---- prep: V fp32 [S][D] -> fragment-ordered (transposed) bf16 ----
// out[ (((t*16 + kc)*32 + db)*64 + lane)*8 + j ] = V[t*256 + kc*16 + (lane>>5)*8 + j][db*32 + (lane&31)]
__global__ void pack_v_kernel(const float* __restrict__ in, unsigned short* __restrict__ out) {
    int idx  = blockIdx.x * 256 + threadIdx.x;
    int lane = idx & 63, db = (idx >> 6) & 31, kc = (idx >> 11) & 15, t = idx >> 15;
    int col = db * 32 + (lane & 31);
    int rowbase = t * 256 + kc * 16 + (lane >> 5) * 8;
    short8 v;
#pragma unroll
    for (int j = 0; j < 8; ++j)
        v[j] = (short)f2bf(in[(size_t)(rowbase + j) * D + col]);
    *(short8*)(out + (size_t)idx * 8) = v;
}

#define SOFTMAX_PHASE(BUF)                                                        \
    {                                                                             \
        _Pragma("unroll")                                                         \
        for (int i = 0; i < 16; ++i) s0[i] += s1[i];                              \
        float mloc = s0[0];                                                       \
        _Pragma("unroll")                                                         \
        for (int r = 1; r < 16; ++r) mloc = fmaxf(mloc, s0[r]);                   \
        mloc = fmaxf(mloc, __shfl_xor(mloc, 32));                                 \
        if (lane < 32) red_m[wid][ln31] = mloc;                                   \
        __syncthreads();                                                          \
        float mt = red_m[0][ln31];                                                \
        _Pragma("unroll")                                                         \
        for (int w = 1; w < NW; ++w) mt = fmaxf(mt, red_m[w][ln31]);              \
        float mnew  = fmaxf(m_run, mt);                                           \
        float alpha = fexp2(m_run - mnew);                                        \
        float pr[16]; float lloc = 0.f;                                           \
        _Pragma("unroll")                                                         \
        for (int r = 0; r < 16; ++r) { pr[r] = fexp2(s0[r] - mnew); lloc += pr[r]; } \
        lloc += __shfl_xor(lloc, 32);                                             \
        if (lane < 32) { red_l[wid][ln31] = lloc; if (wid == 0) alpha_sh[ln31] = alpha; } \
        {                                                                         \
            char* pb = (char*)(&p_lds[BUF][0]) + ln31 * 512;                      \
            _Pragma("unroll")                                                     \
            for (int g = 0; g < 4; ++g) {                                         \
                unsigned p01 = (unsigned)f2bf(pr[4*g+0]) | ((unsigned)f2bf(pr[4*g+1]) << 16); \
                unsigned p23 = (unsigned)f2bf(pr[4*g+2]) | ((unsigned)f2bf(pr[4*g+3]) << 16); \
                uint2 val = make_uint2(p01, p23);                                 \
                int koff = (wid * 32 + 8 * g + 4 * hi) * 2;                       \
                *(uint2*)(pb + (koff ^ swz)) = val;                               \
            }                                                                     \
        }                                                                         \
        __syncthreads();                                                          \
        float lsum = red_l[0][ln31];                                              \
        _Pragma("unroll")                                                         \
        for (int w = 1; w < NW; ++w) lsum += red_l[w][ln31];                      \
        l_run = l_run * alpha + lsum;                                             \
        m_run = mnew;                                                             \
    }

// ---- main fused attention, 1-deep pipelined: phase A = QK(t+1) || PV(t) ----
__global__ __launch_bounds__(NTHR, 2)
void attn_pipe_kernel(const float* __restrict__ Qf,
                      const unsigned short* __restrict__ Kpk,
                      const unsigned short* __restrict__ Vpk,
                      float* __restrict__ Out)
{
    __shared__ unsigned short q_lds[QBLK * D];         // 64KB
    __shared__ unsigned short p_lds[2][QBLK * KVBLK];  // 2 x 16KB double buffer
    __shared__ float red_m[NW][QBLK];
    __shared__ float red_l[NW][QBLK];
    __shared__ float alpha_sh[QBLK];
    __shared__ float invl_sh[QBLK];

    const int tid  = threadIdx.x;
    const int wid  = tid >> 6;
    const int lane = tid & 63;
    const int ln31 = lane & 31;
    const int hi   = (lane >> 5) & 1;
    const int q0   = blockIdx.x * QBLK;
    const int swz  = (ln31 & 15) << 3;

    // ---- stage Q into LDS, scaled by log2(e)/sqrt(D), swizzled ----
    {
        const float cscale = 1.44269504088896340736f / 32.0f;
        const float* qg = Qf + (size_t)q0 * D;
        char* qbw = (char*)q_lds;
#pragma unroll
        for (int it = 0; it < (QBLK * D) / (NTHR * 8); ++it) {
            int idx = (it * NTHR + tid) * 8;
            int qq = idx >> 10, dd = idx & (D - 1);
            const float4* p4 = (const float4*)(qg + idx);
            float4 a = p4[0], b = p4[1];
            short8 v;
            v[0] = (short)f2bf(a.x * cscale); v[1] = (short)f2bf(a.y * cscale);
            v[2] = (short)f2bf(a.z * cscale); v[3] = (short)f2bf(a.w * cscale);
            v[4] = (short)f2bf(b.x * cscale); v[5] = (short)f2bf(b.y * cscale);
            v[6] = (short)f2bf(b.z * cscale); v[7] = (short)f2bf(b.w * cscale);
            lds_w16(qbw + qq * 2048, dd * 2, (qq & 15) << 3, v);
        }
    }

    f32x16 O0, O1, O2, O3, s0, s1;
#pragma unroll
    for (int i = 0; i < 16; ++i) { O0[i] = 0.f; O1[i] = 0.f; O2[i] = 0.f; O3[i] = 0.f; }
    float m_run = -1e30f, l_run = 0.f;

    __syncthreads();

    const char* qb = (const char*)q_lds + ln31 * 2048;

    // ---- prologue: QK(0) + softmax(0) -> p_lds[0] ----
    {
#pragma unroll
        for (int i = 0; i < 16; ++i) { s0[i] = 0.f; s1[i] = 0.f; }
        const unsigned short* kg = Kpk + ((size_t)(0 * 8 + wid) * 4096 + lane) * 8;
        __builtin_amdgcn_s_setprio(1);
#pragma unroll 8
        for (int dc = 0; dc < 64; dc += 2) {
            short8 a0 = *(const short8*)(kg + (size_t)dc * 512);
            short8 b0 = lds_r16(qb, dc * 32 + hi * 16, swz);
            s0 = __builtin_amdgcn_mfma_f32_32x32x16_bf16(a0, b0, s0, 0, 0, 0);
            short8 a1 = *(const short8*)(kg + (size_t)(dc + 1) * 512);
            short8 b1 = lds_r16(qb, (dc + 1) * 32 + hi * 16, swz);
            s1 = __builtin_amdgcn_mfma_f32_32x32x16_bf16(a1, b1, s1, 0, 0, 0);
        }
        __builtin_amdgcn_s_setprio(0);
    }
    SOFTMAX_PHASE(0)   // alpha(0)=0 -> first rescale zeroes O (already 0)

    int cur = 0;
    for (int t = 0; t < NITER; ++t) {
        // ---------- phase A: rescale O; QK(t+1) fused with PV(t) ----------
#pragma unroll
        for (int r = 0; r < 16; ++r) {
            float ar = alpha_sh[(r & 3) + 8 * (r >> 2) + 4 * hi];
            O0[r] *= ar; O1[r] *= ar; O2[r] *= ar; O3[r] *= ar;
        }
        const char* pbase = (const char*)(&p_lds[cur][0]) + ln31 * 512;
        const unsigned short* vg = Vpk + ((size_t)(t * 16) * 2048 + (size_t)wid * 64 + lane) * 8;

        __builtin_amdgcn_s_setprio(1);
        if (t + 1 < NITER) {
#pragma unroll
            for (int i = 0; i < 16; ++i) { s0[i] = 0.f; s1[i] = 0.f; }
            const unsigned short* kg = Kpk + ((size_t)((t + 1) * 8 + wid) * 4096 + lane) * 8;
            short8 pa{};
#pragma unroll 8
            for (int i = 0; i < 64; ++i) {
                const int kc = i >> 2, f = i & 3;
                if (f == 0) pa = lds_r16(pbase, kc * 32 + hi * 16, swz);
                short8 ak = *(const short8*)(kg + (size_t)i * 512);
                short8 bq = lds_r16(qb, i * 32 + hi * 16, swz);
                if (i & 1) s1 = __builtin_amdgcn_mfma_f32_32x32x16_bf16(ak, bq, s1, 0, 0, 0);
                else       s0 = __builtin_amdgcn_mfma_f32_32x32x16_bf16(ak, bq, s0, 0, 0, 0);
                short8 vv = *(const short8*)(vg + (size_t)kc * 16384 + (size_t)f * 4096);
                if      (f == 0) O0 = __builtin_amdgcn_mfma_f32_32x32x16_bf16(pa, vv, O0, 0, 0, 0);
                else if (f == 1) O1 = __builtin_amdgcn_mfma_f32_32x32x16_bf16(pa, vv, O1, 0, 0, 0);
                else if (f == 2) O2 = __builtin_amdgcn_mfma_f32_32x32x16_bf16(pa, vv, O2, 0, 0, 0);
                else             O3 = __builtin_amdgcn_mfma_f32_32x32x16_bf16(pa, vv, O3, 0, 0, 0);
            }
        } else {
#pragma unroll 4
            for (int kc = 0; kc < 16; ++kc) {
                short8 pa = lds_r16(pbase, kc * 32 + hi * 16, swz);
                const unsigned short* vk = vg + (size_t)kc * 16384;
                O0 = __builtin_amdgcn_mfma_f32_32x32x16_bf16(pa, *(const short8*)(vk),         O0, 0, 0, 0);
                O1 = __builtin_amdgcn_mfma_f32_32x32x16_bf16(pa, *(const short8*)(vk + 4096),  O1, 0, 0, 0);
                O2 = __builtin_amdgcn_mfma_f32_32x32x16_bf16(pa, *(const short8*)(vk + 8192),  O2, 0, 0, 0);
                O3 = __builtin_amdgcn_mfma_f32_32x32x16_bf16(pa, *(const short8*)(vk + 12288), O3, 0, 0, 0);
            }
        }
        __builtin_amdgcn_s_setprio(0);

        // ---------- phase B: softmax(t+1) -> p_lds[cur^1] ----------
        if (t + 1 < NITER) {
            if (cur == 0) { SOFTMAX_PHASE(1) } else { SOFTMAX_PHASE(0) }
        }
        cur ^= 1;
    }

    // ---------- epilogue: O /= l ----------
    if (wid == 0 && lane < 32) invl_sh[ln31] = 1.0f / l_run;
    __syncthreads();

    float* outp = Out + (size_t)q0 * D + wid * 32 + ln31;
#pragma unroll
    for (int r = 0; r < 16; ++r) {
        int qrow = (r & 3) + 8 * (r >> 2) + 4 * hi;
        float inv = invl_sh[qrow];
        outp[(size_t)qrow * D + 0]   = O0[r] * inv;
        outp[(size_t)qrow * D + 256] = O1[r] * inv;
        outp[(size_t)qrow * D + 512] = O2[r] * inv;
        outp[(size_t)qrow * D + 768] = O3[r] * inv;
    }
}

// ---- fallback (no workspace): R6 structure reading fp32 directly ----
__global__ __launch_bounds__(NTHR, 2)
void attn_fallback_kernel(const float* __restrict__ Qf,
                          const float* __restrict__ Kf,
                          const float* __restrict__ Vf,
                          float* __restrict__ Out)
{
    __shared__ unsigned short q_lds[QBLK * D];
    __shared__ unsigned short p_lds[1][QBLK * KVBLK];
    __shared__ float red_m[NW][QBLK];
    __shared__ float red_l[NW][QBLK];
    __shared__ float alpha_sh[QBLK];
    __shared__ float invl_sh[QBLK];

    const int tid  = threadIdx.x;
    const int wid  = tid >> 6;
    const int lane = tid & 63;
    const int ln31 = lane & 31;
    const int hi   = (lane >> 5) & 1;
    const int q0   = blockIdx.x * QBLK;
    const int swz  = (ln31 & 15) << 3;

    {
        const float cscale = 1.44269504088896340736f / 32.0f;
        const float* qg = Qf + (size_t)q0 * D;
        char* qbw = (char*)q_lds;
#pragma unroll
        for (int it = 0; it < (QBLK * D) / (NTHR * 8); ++it) {
            int idx = (it * NTHR + tid) * 8;
            int qq = idx >> 10, dd = idx & (D - 1);
            const float4* p4 = (const float4*)(qg + idx);
            float4 a = p4[0], b = p4[1];
            short8 v;
            v[0] = (short)f2bf(a.x * cscale); v[1] = (short)f2bf(a.y * cscale);
            v[2] = (short)f2bf(a.z * cscale); v[3] = (short)f2bf(a.w * cscale);
            v[4] = (short)f2bf(b.x * cscale); v[5] = (short)f2bf(b.y * cscale);
            v[6] = (short)f2bf(b.z * cscale); v[7] = (short)f2bf(b.w * cscale);
            lds_w16(qbw + qq * 2048, dd * 2, (qq & 15) << 3, v);
        }
    }

    f32x16 O0, O1, O2, O3, s0, s1;
#pragma unroll
    for (int i = 0; i < 16; ++i) { O0[i] = 0.f; O1[i] = 0.f; O2[i] = 0.f; O3[i] = 0.f; }
    float m_run = -1e30f, l_run = 0.f;

    __syncthreads();
    const char* qb = (const char*)q_lds + ln31 * 2048;

    for (int t = 0; t < NITER; ++t) {
#pragma unroll
        for (int i = 0; i < 16; ++i) { s0[i] = 0.f; s1[i] = 0.f; }
        const int krow = t * KVBLK + wid * 32 + ln31;
        const float* kg = Kf + (size_t)krow * D + hi * 8;
#pragma unroll 2
        for (int dc = 0; dc < 64; ++dc) {
            const float4* f4 = (const float4*)(kg + dc * 16);
            float4 x = f4[0], y = f4[1];
            short8 a0;
            a0[0] = (short)f2bf(x.x); a0[1] = (short)f2bf(x.y); a0[2] = (short)f2bf(x.z); a0[3] = (short)f2bf(x.w);
            a0[4] = (short)f2bf(y.x); a0[5] = (short)f2bf(y.y); a0[6] = (short)f2bf(y.z); a0[7] = (short)f2bf(y.w);
            short8 b0 = lds_r16(qb, dc * 32 + hi * 16, swz);
            s0 = __builtin_amdgcn_mfma_f32_32x32x16_bf16(a0, b0, s0, 0, 0, 0);
        }
        SOFTMAX_PHASE(0)
#pragma unroll
        for (int r = 0; r < 16; ++r) {
            float ar = alpha_sh[(r & 3) + 8 * (r >> 2) + 4 * hi];
            O0[r] *= ar; O1[r] *= ar; O2[r] *= ar; O3[r] *= ar;
        }
        const char* pbase = (const char*)(&p_lds[0][0]) + ln31 * 512;
        const int dcol0 = wid * 32 + ln31;
#pragma unroll 2
        for (int kc = 0; kc < 16; ++kc) {
            short8 pa = lds_r16(pbase, kc * 32 + hi * 16, swz);
            const float* vf = Vf + (size_t)(t * 256 + kc * 16 + hi * 8) * D + dcol0;
#pragma unroll
            for (int f = 0; f < 4; ++f) {
                short8 vb;
#pragma unroll
                for (int j = 0; j < 8; ++j)
                    vb[j] = (short)f2bf(vf[(size_t)j * D + f * 256]);
                if (f == 0) O0 = __builtin_amdgcn_mfma_f32_32x32x16_bf16(pa, vb, O0, 0, 0, 0);
                if (f == 1) O1 = __builtin_amdgcn_mfma_f32_32x32x16_bf16(pa, vb, O1, 0, 0, 0);
                if (f == 2) O2 = __builtin_amdgcn_mfma_f32_32x32x16_bf16(pa, vb, O2, 0, 0, 0);
                if (f == 3) O3 = __builtin_amdgcn_mfma_f32_32x32x16_bf16(pa, vb, O3, 0, 0, 0);
            }
        }
        __syncthreads();   // protect p_lds reuse next iter
    }

    if (wid == 0 && lane < 32) invl_sh[ln31] = 1.0f / l_run;
    __syncthreads();

    float* outp = Out + (size_t)q0 * D + wid * 32 + ln31;
#pragma unroll
    for (int r = 0; r < 16; ++r) {
        int qrow = (r & 3) + 8 * (r >> 2) + 4 * hi;
        float inv = invl_sh[qrow];
        outp[(size_t)qrow * D + 0]   = O0[r] * inv;
        outp[(size_t)qrow * D + 256] = O1[r] * inv;
        outp[(size_t)qrow * D + 512] = O2[r] * inv;
        outp[(size_t)qrow * D + 768] = O3[r] * inv;
    }
}

extern "C" void kernel_launch(void* const* d_in, const int* in_sizes, int n_in,
                              void* d_out, int out_size, void* d_ws, size_t ws_size,
                              hipStream_t stream)
{
    const float* q = (const float*)d_in[0];
    const float* k = (const float*)d_in[1];
    const float* v = (const float*)d_in[2];
    float* out = (float*)d_out;

    const size_t need = (size_t)2 * S * D * sizeof(unsigned short);  // 33.6 MB
    if (ws_size >= need) {
        unsigned short* kpk = (unsigned short*)d_ws;
        unsigned short* vpk = kpk + (size_t)S * D;
        hipLaunchKernelGGL(pack_k_kernel, dim3(S * D / (256 * 8)), dim3(256), 0, stream, k, kpk);
        hipLaunchKernelGGL(pack_v_kernel, dim3(S * D / (256 * 8)), dim3(256), 0, stream, v, vpk);
        hipLaunchKernelGGL(attn_pipe_kernel, dim3(S / QBLK), dim3(NTHR), 0, stream,
                           q, kpk, vpk, out);
    } else {
        hipLaunchKernelGGL(attn_fallback_kernel, dim3(S / QBLK), dim3(NTHR), 0, stream,
                           q, k, v, out);
    }
}